// Round 11
// baseline (162.177 us; speedup 1.0000x reference)
//
#include <hip/hip_runtime.h>
#include <hip/hip_bf16.h>

// Problem constants (B, C, T, H, KC, WIN) = (4, 512, 1024, 8, 64, 4)
#define Bdim 4
#define Cdim 512
#define Tdim 1024
#define Hn   8
#define KCd  64

// softmax scale folded into q: 1/sqrt(KC) * log2(e) -> scores in exp2 domain
#define QK_SCALE 0.18033688011112042f

typedef __attribute__((ext_vector_type(8))) short bf16x8;   // 8 bf16 = 4 VGPR
typedef __attribute__((ext_vector_type(4))) float f32x4;    // MFMA C/D

// Native f32->bf16 RNE (hardware cvt; compiler pairs into v_cvt_pk_bf16_f32).
__device__ __forceinline__ unsigned short f2bf(float f) {
    __hip_bfloat16 h = __float2bfloat16(f);
    return *reinterpret_cast<unsigned short*>(&h);
}
__device__ __forceinline__ float bf16_f32(unsigned short h) {
    return __uint_as_float(((unsigned)h) << 16);
}
__device__ __forceinline__ void split8(const float* f, bf16x8& h8, bf16x8& l8) {
    #pragma unroll
    for (int e = 0; e < 8; ++e) {
        const unsigned short hh = f2bf(f[e]);
        h8[e] = (short)hh;
        l8[e] = (short)f2bf(f[e] - bf16_f32(hh));
    }
}
__device__ __forceinline__ float max3f(float a, float b, float c) {
    return fmaxf(fmaxf(a, b), c);   // clang fuses to v_max3_f32
}

// LDS 64x64 tile XOR swizzle (only attention's P round-trip)
__device__ __forceinline__ int sw(int row, int col) {
    return (row << 6) + ((((col >> 3) ^ (row & 7)) << 3) | (col & 7));
}
__device__ __forceinline__ bf16x8 fragld(const unsigned short* a, int row, int kstep, int quad) {
    return *(const bf16x8*)&a[(row << 6) + ((((kstep << 2) | quad) ^ (row & 7)) << 3)];
}

// ---------------------------------------------------------------------------
// FRAG-MAJOR plane layouts (hi/lo pre-split):
//  A-plane (stacked [wq;wk;wv;wo], 2048 rows x 512 k):
//    [mtile16:128][kt:16][lane:64][e:8]; elem(m,k): lane=((k>>3)&3)*16+(m&15), e=k&7
//  B-plane (X / ctx, per batch n=1024, k=512):
//    [b*64+ntile16][kt:16][lane:64][e:8]; elem(n,k): lane=((k>>3)&3)*16+(n&15), e=k&7
//  Attn planes per (b,h), 16 time-tiles of 64x64:
//    row-type (Q,K): g=(t>>4)*2+(c>>5), lane=((c>>3)&3)*16+(t&15), e=c&7
//    col-type (V):   g=(c>>4)*2+(t>>5), lane=((t>>3)&3)*16+(c&15), e=t&7
// ---------------------------------------------------------------------------

// prep R10 (unchanged): W path direct; X path via coalesced 32x32 LDS tile.
__global__ __launch_bounds__(256) void prep_kernel(
    const float* __restrict__ wq, const float* __restrict__ wk,
    const float* __restrict__ wv, const float* __restrict__ wo,
    const float* __restrict__ x,
    unsigned short* __restrict__ WAhi, unsigned short* __restrict__ WAlo,
    unsigned short* __restrict__ XBhi, unsigned short* __restrict__ XBlo)
{
    __shared__ float Xl[4][32][33];   // per-wave 32k x 32n tile (+1 pad)

    const int w = threadIdx.x >> 6, lane = threadIdx.x & 63;
    const int l15 = lane & 15, quad = lane >> 4;
    const int task = blockIdx.x * 4 + w;

    if (task < 2048) {
        const int mtile = task >> 4, kt = task & 15;
        const int sel = mtile >> 5;
        const float* W = sel == 0 ? wq : (sel == 1 ? wk : (sel == 2 ? wv : wo));
        const int row = (mtile & 31) * 16 + l15;
        const float* p = W + (size_t)row * Cdim + kt * 32 + quad * 8;
        float f[8];
        *(float4*)&f[0] = *(const float4*)p;
        *(float4*)&f[4] = *(const float4*)(p + 4);
        bf16x8 h8, l8;
        split8(f, h8, l8);
        const size_t base = (size_t)task * 512 + lane * 8;
        *(bf16x8*)(WAhi + base) = h8;
        *(bf16x8*)(WAlo + base) = l8;
    } else {
        const int t2 = task - 2048;                 // 0..2047
        const int b = t2 >> 9, np = (t2 >> 4) & 31, kt = t2 & 15;
        const float* Xb = x + (size_t)b * Cdim * Tdim;
        const int k0 = kt * 32;                     // 32 k-rows
        const int n0 = np * 32;                     // 32 n-cols

        // coalesced read: lane reads 16 consecutive floats of one row
        {
            const int row = lane & 31, ch = lane >> 5;   // ch: 0/1 (16-col half)
            const float* src = Xb + (size_t)(k0 + row) * Tdim + n0 + ch * 16;
            float* dst = &Xl[w][row][ch * 16];
            *(float4*)(dst + 0)  = *(const float4*)(src + 0);
            *(float4*)(dst + 4)  = *(const float4*)(src + 4);
            *(float4*)(dst + 8)  = *(const float4*)(src + 8);
            *(float4*)(dst + 12) = *(const float4*)(src + 12);
        }
        // same-wave LDS dependency: compiler inserts lgkmcnt wait

        // gather frag-major: klocal = quad*8+e, n = n0 + j*16 + l15
        #pragma unroll
        for (int j = 0; j < 2; ++j) {
            float f[8];
            #pragma unroll
            for (int e = 0; e < 8; ++e) f[e] = Xl[w][quad * 8 + e][j * 16 + l15];
            bf16x8 h8, l8;
            split8(f, h8, l8);
            const int ntile = np * 2 + j;
            const size_t base = ((size_t)(b * 1024 + ntile * 16 + kt)) * 512 + lane * 8;
            *(bf16x8*)(XBhi + base) = h8;
            *(bf16x8*)(XBlo + base) = l8;
        }
    }
}

// ---------------------------------------------------------------------------
// QKV GEMM, R11: 2-kt PHASES (BK=64). 8 barriers instead of 16, 48 MFMAs
// per wave per barrier — attacks the m97-style vmcnt-drain-before-barrier
// stall that dominates with tiny per-phase MFMA clusters. A-stage LDS dbuf
// 16->32KB (3 blocks/CU = 96KB OK); B register dbuf 2 kt deep. Arithmetic
// order identical to R6 (bit-identical output).
// ---------------------------------------------------------------------------
__global__ __launch_bounds__(256, 3) void gemm_qkv(
    const unsigned short* __restrict__ Ahi, const unsigned short* __restrict__ Alo,
    const unsigned short* __restrict__ Bhi, const unsigned short* __restrict__ Blo,
    const float* __restrict__ bq, const float* __restrict__ bk, const float* __restrict__ bv,
    unsigned short* __restrict__ qhi, unsigned short* __restrict__ qlo,
    unsigned short* __restrict__ khi, unsigned short* __restrict__ klo,
    unsigned short* __restrict__ vhi, unsigned short* __restrict__ vlo)
{
    __shared__ alignas(16) unsigned short As[2][2][4][2][512]; // [buf][kk][mt][hi/lo]

    const int tid = threadIdx.x;
    const int w = tid >> 6, lane = tid & 63;
    const int l15 = lane & 15, quad = lane >> 4;
    const int lo8 = lane << 3;

    const int id = blockIdx.x;
    const int xcd = id & 7, slot = id >> 3;     // slot 0..95
    const int m64 = slot >> 2;                  // 0..23, block-uniform
    const int col128 = xcd * 4 + (slot & 3);    // 0..31 (4 columns hot per XCD L2)
    const int col = col128 * 4 + w;             // 0..127 = (b, n32), per wave
    const int b = col >> 5, n32 = col & 31;     // b block-uniform
    const int sel = m64 >> 3;
    const int mtb = m64 * 4;                    // mtile16 base (q:0-31 k:32-63 v:64-95)
    const int ntb = b * 64 + n32 * 2;

    // this wave stages mtile mtb+w (hi+lo) each kt
    const unsigned short* Asrc_h = Ahi + (size_t)(mtb + w) * 8192 + lo8;
    const unsigned short* Asrc_l = Alo + (size_t)(mtb + w) * 8192 + lo8;

    f32x4 acc[4][2];
    #pragma unroll
    for (int i = 0; i < 4; ++i)
        #pragma unroll
        for (int j = 0; j < 2; ++j) acc[i][j] = (f32x4){0.f, 0.f, 0.f, 0.f};

    bf16x8 Bh[2][2][2], Bl[2][2][2];            // [buf][kk][nt]
    // prologue: load B + stage A for phase 0 (kt 0,1)
    #pragma unroll
    for (int kk = 0; kk < 2; ++kk) {
        const int kn = kk * 512;
        #pragma unroll
        for (int nt = 0; nt < 2; ++nt) {
            const size_t o = (size_t)(ntb + nt) * 8192 + kn + lo8;
            Bh[0][kk][nt] = *(const bf16x8*)(Bhi + o);
            Bl[0][kk][nt] = *(const bf16x8*)(Blo + o);
        }
        *(bf16x8*)&As[0][kk][w][0][lo8] = *(const bf16x8*)(Asrc_h + kn);
        *(bf16x8*)&As[0][kk][w][1][lo8] = *(const bf16x8*)(Asrc_l + kn);
    }
    __syncthreads();

    for (int ph = 0; ph < 8; ++ph) {
        const int cur = ph & 1, nxt = cur ^ 1;
        bf16x8 stgh[2], stgl[2];
        if (ph < 7) {
            #pragma unroll
            for (int kk = 0; kk < 2; ++kk) {
                const int kn = ((ph + 1) * 2 + kk) * 512;
                // issue next-phase loads EARLY (latency hidden under 48 MFMAs)
                stgh[kk] = *(const bf16x8*)(Asrc_h + kn);
                stgl[kk] = *(const bf16x8*)(Asrc_l + kn);
                #pragma unroll
                for (int nt = 0; nt < 2; ++nt) {
                    const size_t o = (size_t)(ntb + nt) * 8192 + kn + lo8;
                    Bh[nxt][kk][nt] = *(const bf16x8*)(Bhi + o);
                    Bl[nxt][kk][nt] = *(const bf16x8*)(Blo + o);
                }
            }
        }
        #pragma unroll
        for (int kk = 0; kk < 2; ++kk) {
            bf16x8 Afh[4], Afl[4];
            #pragma unroll
            for (int mt = 0; mt < 4; ++mt) {
                Afh[mt] = *(const bf16x8*)&As[cur][kk][mt][0][lo8];
                Afl[mt] = *(const bf16x8*)&As[cur][kk][mt][1][lo8];
            }
            #pragma unroll
            for (int mt = 0; mt < 4; ++mt)
                #pragma unroll
                for (int nt = 0; nt < 2; ++nt) {
                    f32x4 c = acc[mt][nt];
                    c = __builtin_amdgcn_mfma_f32_16x16x32_bf16(Afh[mt], Bh[cur][kk][nt], c, 0, 0, 0);
                    c = __builtin_amdgcn_mfma_f32_16x16x32_bf16(Afh[mt], Bl[cur][kk][nt], c, 0, 0, 0);
                    c = __builtin_amdgcn_mfma_f32_16x16x32_bf16(Afl[mt], Bh[cur][kk][nt], c, 0, 0, 0);
                    acc[mt][nt] = c;
                }
        }
        if (ph < 7) {
            // write staged A AFTER the MFMA cluster (vmcnt drains here, 1x/phase)
            #pragma unroll
            for (int kk = 0; kk < 2; ++kk) {
                *(bf16x8*)&As[nxt][kk][w][0][lo8] = stgh[kk];
                *(bf16x8*)&As[nxt][kk][w][1][lo8] = stgl[kk];
            }
        }
        __syncthreads();
    }

    // ---- epilogue: D[m=quad*4+r (channel)][n=l15 (time)] -> attn planes ----
    const int head = m64 & 7;
    const size_t hbase = ((size_t)(b * Hn + head) * 16) << 12;
    if (sel < 2) {
        const float* Bv = sel == 0 ? bq : bk;
        unsigned short* ph = sel == 0 ? qhi : khi;
        unsigned short* pl = sel == 0 ? qlo : klo;
        const float qscale = sel == 0 ? QK_SCALE : 1.0f;
        #pragma unroll
        for (int mt = 0; mt < 4; ++mt) {
            const int c0 = mt * 16 + quad * 4;          // channel-in-head base
            float bb[4];
            #pragma unroll
            for (int r = 0; r < 4; ++r) bb[r] = Bv[head * 64 + c0 + r];
            const int lane_out = (((c0 >> 3) & 3) << 4) + l15;
            const int e0 = c0 & 7;                      // 0 or 4
            const int cg = c0 >> 5;
            #pragma unroll
            for (int nt = 0; nt < 2; ++nt) {
                const int tile = n32 >> 1;
                const int rhi = (n32 & 1) * 2 + nt;     // (t&63)>>4
                const int g = rhi * 2 + cg;
                const size_t off = hbase + ((size_t)tile << 12) + g * 512
                                 + (size_t)lane_out * 8 + e0;
                ushort4 h4, l4;
                #pragma unroll
                for (int r = 0; r < 4; ++r) {
                    const float v = (acc[mt][nt][r] + bb[r]) * qscale;
                    const unsigned short hh = f2bf(v);
                    ((unsigned short*)&h4)[r] = hh;
                    ((unsigned short*)&l4)[r] = f2bf(v - bf16_f32(hh));
                }
                *(ushort4*)(ph + off) = h4;
                *(ushort4*)(pl + off) = l4;
            }
        }
    } else {
        #pragma unroll
        for (int mt = 0; mt < 4; ++mt) {
            const int c0 = mt * 16 + quad * 4;
            float bb[4];
            #pragma unroll
            for (int r = 0; r < 4; ++r) bb[r] = bv[head * 64 + c0 + r];
            #pragma unroll
            for (int nt = 0; nt < 2; ++nt) {
                const int t = n32 * 32 + nt * 16 + l15;
                const int tile = t >> 6, jl = t & 63;
                const int jg = jl >> 5, lanej = ((jl >> 3) & 3) << 4;
                const int e = jl & 7;
                const size_t tb = hbase + ((size_t)tile << 12);
                #pragma unroll
                for (int r = 0; r < 4; ++r) {
                    const int c = c0 + r;
                    const int g = mt * 2 + jg;          // c>>4 == mt here
                    const int lane_v = lanej + (c & 15);
                    const float v = acc[mt][nt][r] + bb[r];
                    const unsigned short hh = f2bf(v);
                    const size_t off = tb + g * 512 + (size_t)lane_v * 8 + e;
                    vhi[off] = hh;
                    vlo[off] = f2bf(v - bf16_f32(hh));
                }
            }
        }
    }
}

// ---------------------------------------------------------------------------
// Out-projection GEMM, R10 (unchanged): 64m x 64n block, 2x2 wave grid,
// BOTH operands staged + shared. 512 blocks (2/CU).
// ---------------------------------------------------------------------------
__global__ __launch_bounds__(256) void gemm_out(
    const unsigned short* __restrict__ Ahi, const unsigned short* __restrict__ Alo,
    const unsigned short* __restrict__ Bhi, const unsigned short* __restrict__ Blo,
    const float* __restrict__ bo, float* __restrict__ out)
{
    __shared__ alignas(16) unsigned short St[2][16][512];  // chunks: 0-7 A, 8-15 B

    const int tid = threadIdx.x;
    const int w = tid >> 6, lane = tid & 63;
    const int l15 = lane & 15, quad = lane >> 4;
    const int lo8 = lane << 3;

    const int id = blockIdx.x;
    const int xcd = id & 7, slot = id >> 3;       // 0..63
    const int ncol64 = xcd * 8 + (slot >> 3);     // 0..63 (8 n64-cols per XCD)
    const int mg8 = slot & 7;                     // 0..7 (64-row Wo group)
    const int wr = w >> 1, wc = w & 1;            // 2x2 wave grid
    const int m32 = mg8 * 2 + wr;                 // 0..15
    const int n32g = ncol64 * 2 + wc;             // 0..127
    const int b = n32g >> 5, n32 = n32g & 31;
    const int nb = (ncol64 & 15) * 4;             // block ntile base (in batch)
    const int bb64 = (ncol64 >> 4) * 64;          // batch ntile base

    // this wave's 4 staging chunks (chunk c = w*4+i)
    const unsigned short* csrc[4];
    #pragma unroll
    for (int i = 0; i < 4; ++i) {
        const int c = w * 4 + i;
        if (c < 8) {
            const int mt = c >> 1;
            csrc[i] = ((c & 1) ? Alo : Ahi) + (size_t)(96 + mg8 * 4 + mt) * 8192 + lo8;
        } else {
            const int nt = (c - 8) >> 1;
            csrc[i] = ((c & 1) ? Blo : Bhi) + (size_t)(bb64 + nb + nt) * 8192 + lo8;
        }
    }

    f32x4 acc[2][2];
    #pragma unroll
    for (int i = 0; i < 2; ++i)
        #pragma unroll
        for (int j = 0; j < 2; ++j) acc[i][j] = (f32x4){0.f, 0.f, 0.f, 0.f};

    // prologue: stage kt=0
    #pragma unroll
    for (int i = 0; i < 4; ++i)
        *(bf16x8*)&St[0][w * 4 + i][lo8] = *(const bf16x8*)csrc[i];
    __syncthreads();

    for (int kt = 0; kt < 16; ++kt) {
        const int cur = kt & 1, nxt = cur ^ 1;
        bf16x8 stg[4];
        if (kt < 15) {
            const int kn = (kt + 1) * 512;
            #pragma unroll
            for (int i = 0; i < 4; ++i)
                stg[i] = *(const bf16x8*)(csrc[i] + kn);
        }
        bf16x8 Afh[2], Afl[2], Bfh[2], Bfl[2];
        #pragma unroll
        for (int i = 0; i < 2; ++i) {
            const int lm = wr * 2 + i;
            Afh[i] = *(const bf16x8*)&St[cur][lm * 2 + 0][lo8];
            Afl[i] = *(const bf16x8*)&St[cur][lm * 2 + 1][lo8];
            const int ln = wc * 2 + i;
            Bfh[i] = *(const bf16x8*)&St[cur][8 + ln * 2 + 0][lo8];
            Bfl[i] = *(const bf16x8*)&St[cur][8 + ln * 2 + 1][lo8];
        }
        #pragma unroll
        for (int mt = 0; mt < 2; ++mt)
            #pragma unroll
            for (int nt = 0; nt < 2; ++nt) {
                f32x4 c = acc[mt][nt];
                c = __builtin_amdgcn_mfma_f32_16x16x32_bf16(Afh[mt], Bfh[nt], c, 0, 0, 0);
                c = __builtin_amdgcn_mfma_f32_16x16x32_bf16(Afh[mt], Bfl[nt], c, 0, 0, 0);
                c = __builtin_amdgcn_mfma_f32_16x16x32_bf16(Afl[mt], Bfh[nt], c, 0, 0, 0);
                acc[mt][nt] = c;
            }
        if (kt < 15) {
            #pragma unroll
            for (int i = 0; i < 4; ++i)
                *(bf16x8*)&St[nxt][w * 4 + i][lo8] = stg[i];
        }
        __syncthreads();
    }

    float* Ob = out + (size_t)b * Cdim * Tdim;
    #pragma unroll
    for (int mt = 0; mt < 2; ++mt) {
        const int m = m32 * 32 + mt * 16 + quad * 4;
        float bb[4];
        #pragma unroll
        for (int r = 0; r < 4; ++r) bb[r] = bo[m + r];
        #pragma unroll
        for (int nt = 0; nt < 2; ++nt) {
            const int t = n32 * 32 + nt * 16 + l15;
            #pragma unroll
            for (int r = 0; r < 4; ++r)
                Ob[(size_t)(m + r) * Tdim + t] = acc[mt][nt][r] + bb[r];
        }
    }
}

// ---------------------------------------------------------------------------
// R9 attention (measured 54-55 us, best) — UNCHANGED.
// ---------------------------------------------------------------------------
__global__ __launch_bounds__(256) void attn_mfma(
    const unsigned short* __restrict__ qhi, const unsigned short* __restrict__ qlo,
    const unsigned short* __restrict__ khi, const unsigned short* __restrict__ klo,
    const unsigned short* __restrict__ vhi, const unsigned short* __restrict__ vlo,
    const float* __restrict__ ek,   // [9,64]
    const float* __restrict__ ev,   // [9,64]
    unsigned short* __restrict__ cxhi, unsigned short* __restrict__ cxlo)
{
    __shared__ alignas(16) unsigned short psh[4096], psl[4096];
    __shared__ float rk[576];       // rel-k logits (exp2 domain via q scale)
    __shared__ float evs[576];
    __shared__ float bandp[576];    // f32 post-exp P band values, wave-private rows

    const int tid = threadIdx.x;
    int it, h, b;
    {
        const int n = blockIdx.x;
        const int xcd = n & 7, slot = n >> 3;
        const int pair = (xcd << 2) | (slot >> 4);
        it = slot & 15;
        b = pair >> 3;
        h = pair & 7;
    }
    const int i0 = it * 64;
    const int lane = tid & 63, w = tid >> 6;
    const int l15 = lane & 15, quad = lane >> 4;
    const int m_blk = w * 16 + l15;
    const int lo8 = lane << 3;

    const size_t bh16 = (size_t)(b * Hn + h) * 16;

    bf16x8 qfh[2], qfl[2];
    {
        const unsigned short* qth = qhi + ((bh16 + it) << 12);
        const unsigned short* qtl = qlo + ((bh16 + it) << 12);
        #pragma unroll
        for (int ks = 0; ks < 2; ++ks) {
            qfh[ks] = *(const bf16x8*)(qth + (((w << 1) | ks) << 9) + lo8);
            qfl[ks] = *(const bf16x8*)(qtl + (((w << 1) | ks) << 9) + lo8);
        }
    }

    bf16x8 ekh[2], ekl[2];
    #pragma unroll
    for (int ks = 0; ks < 2; ++ks) {
        #pragma unroll
        for (int j = 0; j < 8; ++j) { ekh[ks][j] = 0; ekl[ks][j] = 0; }
        if (l15 < 9) {
            #pragma unroll
            for (int j = 0; j < 8; ++j) {
                const float v = ek[l15 * 64 + ks * 32 + quad * 8 + j];
                const unsigned short hh = f2bf(v);
                ekh[ks][j] = (short)hh;
                ekl[ks][j] = (short)f2bf(v - bf16_f32(hh));
            }
        }
    }

    {
        f32x4 rkD = (f32x4){0.f, 0.f, 0.f, 0.f};
        #pragma unroll
        for (int ks = 0; ks < 2; ++ks) {
            rkD = __builtin_amdgcn_mfma_f32_16x16x32_bf16(qfh[ks], ekh[ks], rkD, 0, 0, 0);
            rkD = __builtin_amdgcn_mfma_f32_16x16x32_bf16(qfh[ks], ekl[ks], rkD, 0, 0, 0);
            rkD = __builtin_amdgcn_mfma_f32_16x16x32_bf16(qfl[ks], ekh[ks], rkD, 0, 0, 0);
        }
        if (l15 < 9) {
            // q is pre-scaled -> rkD already carries QK_SCALE
            #pragma unroll
            for (int r = 0; r < 4; ++r)
                rk[(w * 16 + quad * 4 + r) * 9 + l15] = rkD[r];
        }
    }
    for (int idx = tid; idx < 576; idx += 256) evs[idx] = ev[idx];
    __syncthreads();   // the ONLY barrier

    // hoisted P-store swizzle addresses (constant per thread)
    int osw[4];
    #pragma unroll
    for (int jt = 0; jt < 4; ++jt) osw[jt] = sw(m_blk, jt * 16 + quad * 4);

    float m_run = -1e30f, l_run = 0.f;
    f32x4 Oc[4];
    #pragma unroll
    for (int ct = 0; ct < 4; ++ct) Oc[ct] = (f32x4){0.f, 0.f, 0.f, 0.f};

    const unsigned short* kh0 = khi + (bh16 << 12);
    const unsigned short* kl0 = klo + (bh16 << 12);
    const unsigned short* vh0 = vhi + (bh16 << 12);
    const unsigned short* vl0 = vlo + (bh16 << 12);

    for (int t = 0; t < 16; ++t) {
        const int j0 = t << 6;
        const size_t tb = (size_t)t << 12;
        const unsigned short* kht = kh0 + tb;
        const unsigned short* klt = kl0 + tb;
        const unsigned short* vht = vh0 + tb;
        const unsigned short* vlt = vl0 + tb;

        bf16x8 vbh[2][4], vbl[2][4];
        #pragma unroll
        for (int ks = 0; ks < 2; ++ks)
            #pragma unroll
            for (int ct = 0; ct < 4; ++ct) {
                vbh[ks][ct] = *(const bf16x8*)(vht + (((ct << 1) | ks) << 9) + lo8);
                vbl[ks][ct] = *(const bf16x8*)(vlt + (((ct << 1) | ks) << 9) + lo8);
            }

        f32x4 Sc[4];
        #pragma unroll
        for (int jt = 0; jt < 4; ++jt) Sc[jt] = (f32x4){0.f, 0.f, 0.f, 0.f};
        #pragma unroll
        for (int ks = 0; ks < 2; ++ks) {
            bf16x8 ah[4], al[4];
            #pragma unroll
            for (int jt = 0; jt < 4; ++jt) {
                ah[jt] = *(const bf16x8*)(kht + (((jt << 1) | ks) << 9) + lo8);
                al[jt] = *(const bf16x8*)(klt + (((jt << 1) | ks) << 9) + lo8);
            }
            #pragma unroll
            for (int jt = 0; jt < 4; ++jt) {
                Sc[jt] = __builtin_amdgcn_mfma_f32_16x16x32_bf16(ah[jt], qfh[ks], Sc[jt], 0, 0, 0);
                Sc[jt] = __builtin_amdgcn_mfma_f32_16x16x32_bf16(ah[jt], qfl[ks], Sc[jt], 0, 0, 0);
                Sc[jt] = __builtin_amdgcn_mfma_f32_16x16x32_bf16(al[jt], qfh[ks], Sc[jt], 0, 0, 0);
            }
        }

        const int dt = j0 - i0;
        const bool diag = (dt >= -67 && dt <= 67);
        if (diag) {
            #pragma unroll
            for (int jt = 0; jt < 4; ++jt) {
                const int db = dt + jt * 16 + quad * 4 - m_blk;
                #pragma unroll
                for (int r = 0; r < 4; ++r) {
                    const int d = db + r;
                    if ((unsigned)(d + 4) <= 8u) Sc[jt][r] += rk[m_blk * 9 + d + 4];
                }
            }
        }

        // row max: max3-shaped tree (v_max3_f32)
        const float t0m = max3f(Sc[0][0], Sc[0][1], Sc[0][2]);
        const float t1m = max3f(Sc[0][3], Sc[1][0], Sc[1][1]);
        const float t2m = max3f(Sc[1][2], Sc[1][3], Sc[2][0]);
        const float t3m = max3f(Sc[2][1], Sc[2][2], Sc[2][3]);
        const float t4m = max3f(Sc[3][0], Sc[3][1], Sc[3][2]);
        const float mt = fmaxf(max3f(t0m, t1m, t2m), max3f(t3m, t4m, Sc[3][3]));
        float mr = fmaxf(mt, __shfl_xor(mt, 16));
        mr = fmaxf(mr, __shfl_xor(mr, 32));

        // wave-uniform rescale skip: when no row's max grows, alpha==1 exactly
        if (__any(mr > m_run)) {
            const float mn = fmaxf(m_run, mr);
            const float alpha = __builtin_amdgcn_exp2f(m_run - mn);
            m_run = mn;
            l_run *= alpha;
            const float al0 = __shfl(alpha, quad * 4 + 0);
            const float al1 = __shfl(alpha, quad * 4 + 1);
            const float al2 = __shfl(alpha, quad * 4 + 2);
            const float al3 = __shfl(alpha, quad * 4 + 3);
            #pragma unroll
            for (int ct = 0; ct < 4; ++ct) {
                Oc[ct][0] *= al0; Oc[ct][1] *= al1; Oc[ct][2] *= al2; Oc[ct][3] *= al3;
            }
        }

        #pragma unroll
        for (int jt = 0; jt < 4; ++jt)
            #pragma unroll
            for (int r = 0; r < 4; ++r)
                Sc[jt][r] = __builtin_amdgcn_exp2f(Sc[jt][r] - m_run);

        float rs = ((Sc[0][0] + Sc[0][1]) + (Sc[0][2] + Sc[0][3]))
                 + ((Sc[1][0] + Sc[1][1]) + (Sc[1][2] + Sc[1][3]))
                 + ((Sc[2][0] + Sc[2][1]) + (Sc[2][2] + Sc[2][3]))
                 + ((Sc[3][0] + Sc[3][1]) + (Sc[3][2] + Sc[3][3]));
        rs += __shfl_xor(rs, 16);
        rs += __shfl_xor(rs, 32);
        l_run += rs;

        // f32 band scatter for rel-v (wave-private rows, read after PV)
        if (diag) {
            #pragma unroll
            for (int jt = 0; jt < 4; ++jt) {
                const int db = dt + jt * 16 + quad * 4 - m_blk;
                #pragma unroll
                for (int r = 0; r < 4; ++r) {
                    const int d = db + r;
                    if ((unsigned)(d + 4) <= 8u) bandp[m_blk * 9 + d + 4] = Sc[jt][r];
                }
            }
        }

        // P hi/lo split via native cvt (compiler pairs into v_cvt_pk_bf16_f32)
        #pragma unroll
        for (int jt = 0; jt < 4; ++jt) {
            ushort4 ph, pl;
            ph.x = f2bf(Sc[jt][0]); pl.x = f2bf(Sc[jt][0] - bf16_f32(ph.x));
            ph.y = f2bf(Sc[jt][1]); pl.y = f2bf(Sc[jt][1] - bf16_f32(ph.y));
            ph.z = f2bf(Sc[jt][2]); pl.z = f2bf(Sc[jt][2] - bf16_f32(ph.z));
            ph.w = f2bf(Sc[jt][3]); pl.w = f2bf(Sc[jt][3] - bf16_f32(ph.w));
            *(ushort4*)&psh[osw[jt]] = ph;
            *(ushort4*)&psl[osw[jt]] = pl;
        }
        // no barrier: wave reads only its own 16 P rows

        #pragma unroll
        for (int ks = 0; ks < 2; ++ks) {
            bf16x8 pah = fragld(psh, m_blk, ks, quad);
            bf16x8 pal = fragld(psl, m_blk, ks, quad);
            #pragma unroll
            for (int ct = 0; ct < 4; ++ct) {
                Oc[ct] = __builtin_amdgcn_mfma_f32_16x16x32_bf16(pah, vbh[ks][ct], Oc[ct], 0, 0, 0);
                Oc[ct] = __builtin_amdgcn_mfma_f32_16x16x32_bf16(pah, vbl[ks][ct], Oc[ct], 0, 0, 0);
                Oc[ct] = __builtin_amdgcn_mfma_f32_16x16x32_bf16(pal, vbh[ks][ct], Oc[ct], 0, 0, 0);
            }
        }

        if (diag) {
            #pragma unroll
            for (int r = 0; r < 4; ++r) {
                const int mrow = w * 16 + quad * 4 + r;
                const int ig = i0 + mrow;
                #pragma unroll
                for (int e = 0; e < 9; ++e) {
                    const int jl = ig + e - 4 - j0;
                    if ((unsigned)jl < 64u) {
                        const float p = bandp[mrow * 9 + e];   // f32 broadcast read
                        #pragma unroll
                        for (int ct = 0; ct < 4; ++ct)
                            Oc[ct][r] += p * evs[e * 64 + ct * 16 + l15];
                    }
                }
            }
        }
    }

    // ---- epilogue: normalize, write ctx B-operand frag-major hi/lo planes ----
    const float rlv = 1.f / l_run;
    float rl[4];
    rl[0] = __shfl(rlv, quad * 4 + 0);
    rl[1] = __shfl(rlv, quad * 4 + 1);
    rl[2] = __shfl(rlv, quad * 4 + 2);
    rl[3] = __shfl(rlv, quad * 4 + 3);
    const int ntile16 = it * 4 + w;
    const int e = l15 & 7;
    #pragma unroll
    for (int ct = 0; ct < 4; ++ct) {
        const int cl = ct * 16 + l15;                    // channel within head
        const int ktc = h * 2 + (cl >> 5);
        const int lane_c = (((ct * 2 + (l15 >> 3)) & 3) << 4) + quad * 4;   // + r
        const size_t base = (((size_t)(b * 64 + ntile16)) * 16 + ktc) * 512;
        #pragma unroll
        for (int r = 0; r < 4; ++r) {
            const float v = Oc[ct][r] * rl[r];
            const unsigned short hh = f2bf(v);
            const size_t off = base + (size_t)(lane_c + r) * 8 + e;
            cxhi[off] = hh;
            cxlo[off] = f2bf(v - bf16_f32(hh));
        }
    }
}

// ---------------------------------------------------------------------------
extern "C" void kernel_launch(void* const* d_in, const int* in_sizes, int n_in,
                              void* d_out, int out_size, void* d_ws, size_t ws_size,
                              hipStream_t stream) {
    const float* x  = (const float*)d_in[0];
    const float* wq = (const float*)d_in[1];
    const float* bq = (const float*)d_in[2];
    const float* wk = (const float*)d_in[3];
    const float* bk = (const float*)d_in[4];
    const float* wv = (const float*)d_in[5];
    const float* bv = (const float*)d_in[6];
    const float* wo = (const float*)d_in[7];
    const float* bo = (const float*)d_in[8];
    const float* ek = (const float*)d_in[9];
    const float* ev = (const float*)d_in[10];
    float* out = (float*)d_out;

    const size_t PW = 2048u * 512u;          // stacked-W plane elements
    const size_t PX = 4u * 1024u * 512u;     // X / ctx / attn plane elements
    unsigned short* WAhi = (unsigned short*)d_ws;
    unsigned short* WAlo = WAhi + PW;
    unsigned short* XBhi = WAlo + PW;
    unsigned short* XBlo = XBhi + PX;
    unsigned short* qhi  = XBlo + PX;
    unsigned short* qlo  = qhi + PX;
    unsigned short* khi  = qlo + PX;
    unsigned short* klo  = khi + PX;
    unsigned short* vhi  = klo + PX;
    unsigned short* vlo  = vhi + PX;
    unsigned short* cxhi = vlo + PX;
    unsigned short* cxlo = cxhi + PX;

    // one-time split/convert of W and X into frag-major planes
    prep_kernel<<<dim3(1024), 256, 0, stream>>>(
        wq, wk, wv, wo, x, WAhi, WAlo, XBhi, XBlo);

    // QKV projection: 768 blocks (3/CU), 2-kt phases (8 barriers) -> attn planes
    gemm_qkv<<<dim3(768), 256, 0, stream>>>(
        WAhi, WAlo, XBhi, XBlo, bq, bk, bv,
        qhi, qlo, khi, klo, vhi, vlo);

    // barrier-free MFMA flash attention (instruction-diet) -> ctx planes
    attn_mfma<<<dim3(512), 256, 0, stream>>>(
        qhi, qlo, khi, klo, vhi, vlo, ek, ev, cxhi, cxlo);

    // output projection: 512 blocks (2/CU), A+B dual-shared LDS dbuf -> fp32
    gemm_out<<<dim3(512), 256, 0, stream>>>(
        WAhi, WAlo, cxhi, cxlo, bo, out);
}

// Round 12
// 159.551 us; speedup vs baseline: 1.0165x; 1.0165x over previous
//
#include <hip/hip_runtime.h>
#include <hip/hip_bf16.h>

// Problem constants (B, C, T, H, KC, WIN) = (4, 512, 1024, 8, 64, 4)
#define Bdim 4
#define Cdim 512
#define Tdim 1024
#define Hn   8
#define KCd  64

// softmax scale folded into q: 1/sqrt(KC) * log2(e) -> scores in exp2 domain
#define QK_SCALE 0.18033688011112042f

typedef __attribute__((ext_vector_type(8))) short bf16x8;   // 8 bf16 = 4 VGPR
typedef __attribute__((ext_vector_type(4))) float f32x4;    // MFMA C/D

// Native f32->bf16 RNE (hardware cvt; compiler pairs into v_cvt_pk_bf16_f32).
__device__ __forceinline__ unsigned short f2bf(float f) {
    __hip_bfloat16 h = __float2bfloat16(f);
    return *reinterpret_cast<unsigned short*>(&h);
}
__device__ __forceinline__ float bf16_f32(unsigned short h) {
    return __uint_as_float(((unsigned)h) << 16);
}
__device__ __forceinline__ void split8(const float* f, bf16x8& h8, bf16x8& l8) {
    #pragma unroll
    for (int e = 0; e < 8; ++e) {
        const unsigned short hh = f2bf(f[e]);
        h8[e] = (short)hh;
        l8[e] = (short)f2bf(f[e] - bf16_f32(hh));
    }
}
__device__ __forceinline__ float max3f(float a, float b, float c) {
    return fmaxf(fmaxf(a, b), c);   // clang fuses to v_max3_f32
}

// LDS 64x64 tile XOR swizzle (only attention's P round-trip)
__device__ __forceinline__ int sw(int row, int col) {
    return (row << 6) + ((((col >> 3) ^ (row & 7)) << 3) | (col & 7));
}
__device__ __forceinline__ bf16x8 fragld(const unsigned short* a, int row, int kstep, int quad) {
    return *(const bf16x8*)&a[(row << 6) + ((((kstep << 2) | quad) ^ (row & 7)) << 3)];
}

// ---------------------------------------------------------------------------
// FRAG-MAJOR plane layouts (hi/lo pre-split):
//  A-plane (stacked [wq;wk;wv;wo], 2048 rows x 512 k):
//    [mtile16:128][kt:16][lane:64][e:8]; elem(m,k): lane=((k>>3)&3)*16+(m&15), e=k&7
//  B-plane (X / ctx, per batch n=1024, k=512):
//    [b*64+ntile16][kt:16][lane:64][e:8]; elem(n,k): lane=((k>>3)&3)*16+(n&15), e=k&7
//  Attn planes per (b,h), 16 time-tiles of 64x64:
//    row-type (Q,K): g=(t>>4)*2+(c>>5), lane=((c>>3)&3)*16+(t&15), e=c&7
//    col-type (V):   g=(c>>4)*2+(t>>5), lane=((t>>3)&3)*16+(c&15), e=t&7
// ---------------------------------------------------------------------------

// prep R10 (unchanged): W path direct; X path via coalesced 32x32 LDS tile.
__global__ __launch_bounds__(256) void prep_kernel(
    const float* __restrict__ wq, const float* __restrict__ wk,
    const float* __restrict__ wv, const float* __restrict__ wo,
    const float* __restrict__ x,
    unsigned short* __restrict__ WAhi, unsigned short* __restrict__ WAlo,
    unsigned short* __restrict__ XBhi, unsigned short* __restrict__ XBlo)
{
    __shared__ float Xl[4][32][33];   // per-wave 32k x 32n tile (+1 pad)

    const int w = threadIdx.x >> 6, lane = threadIdx.x & 63;
    const int l15 = lane & 15, quad = lane >> 4;
    const int task = blockIdx.x * 4 + w;

    if (task < 2048) {
        const int mtile = task >> 4, kt = task & 15;
        const int sel = mtile >> 5;
        const float* W = sel == 0 ? wq : (sel == 1 ? wk : (sel == 2 ? wv : wo));
        const int row = (mtile & 31) * 16 + l15;
        const float* p = W + (size_t)row * Cdim + kt * 32 + quad * 8;
        float f[8];
        *(float4*)&f[0] = *(const float4*)p;
        *(float4*)&f[4] = *(const float4*)(p + 4);
        bf16x8 h8, l8;
        split8(f, h8, l8);
        const size_t base = (size_t)task * 512 + lane * 8;
        *(bf16x8*)(WAhi + base) = h8;
        *(bf16x8*)(WAlo + base) = l8;
    } else {
        const int t2 = task - 2048;                 // 0..2047
        const int b = t2 >> 9, np = (t2 >> 4) & 31, kt = t2 & 15;
        const float* Xb = x + (size_t)b * Cdim * Tdim;
        const int k0 = kt * 32;                     // 32 k-rows
        const int n0 = np * 32;                     // 32 n-cols

        // coalesced read: lane reads 16 consecutive floats of one row
        {
            const int row = lane & 31, ch = lane >> 5;   // ch: 0/1 (16-col half)
            const float* src = Xb + (size_t)(k0 + row) * Tdim + n0 + ch * 16;
            float* dst = &Xl[w][row][ch * 16];
            *(float4*)(dst + 0)  = *(const float4*)(src + 0);
            *(float4*)(dst + 4)  = *(const float4*)(src + 4);
            *(float4*)(dst + 8)  = *(const float4*)(src + 8);
            *(float4*)(dst + 12) = *(const float4*)(src + 12);
        }
        // same-wave LDS dependency: compiler inserts lgkmcnt wait

        // gather frag-major: klocal = quad*8+e, n = n0 + j*16 + l15
        #pragma unroll
        for (int j = 0; j < 2; ++j) {
            float f[8];
            #pragma unroll
            for (int e = 0; e < 8; ++e) f[e] = Xl[w][quad * 8 + e][j * 16 + l15];
            bf16x8 h8, l8;
            split8(f, h8, l8);
            const int ntile = np * 2 + j;
            const size_t base = ((size_t)(b * 1024 + ntile * 16 + kt)) * 512 + lane * 8;
            *(bf16x8*)(XBhi + base) = h8;
            *(bf16x8*)(XBlo + base) = l8;
        }
    }
}

// ---------------------------------------------------------------------------
// QKV GEMM, R6/R10 (measured best, reverted after R11's BK=64 was neutral):
// A-SHARED block, 16KB LDS dbuf for A, B per-wave registers. 768 blocks
// = 3/CU. q pre-scaled by QK_SCALE.
// ---------------------------------------------------------------------------
__global__ __launch_bounds__(256, 3) void gemm_qkv(
    const unsigned short* __restrict__ Ahi, const unsigned short* __restrict__ Alo,
    const unsigned short* __restrict__ Bhi, const unsigned short* __restrict__ Blo,
    const float* __restrict__ bq, const float* __restrict__ bk, const float* __restrict__ bv,
    unsigned short* __restrict__ qhi, unsigned short* __restrict__ qlo,
    unsigned short* __restrict__ khi, unsigned short* __restrict__ klo,
    unsigned short* __restrict__ vhi, unsigned short* __restrict__ vlo)
{
    __shared__ alignas(16) unsigned short As[2][4][2][512];  // [buf][mt][hi/lo][512]

    const int tid = threadIdx.x;
    const int w = tid >> 6, lane = tid & 63;
    const int l15 = lane & 15, quad = lane >> 4;
    const int lo8 = lane << 3;

    const int id = blockIdx.x;
    const int xcd = id & 7, slot = id >> 3;     // slot 0..95
    const int m64 = slot >> 2;                  // 0..23, block-uniform
    const int col128 = xcd * 4 + (slot & 3);    // 0..31 (4 columns hot per XCD L2)
    const int col = col128 * 4 + w;             // 0..127 = (b, n32), per wave
    const int b = col >> 5, n32 = col & 31;     // b block-uniform
    const int sel = m64 >> 3;
    const int mtb = m64 * 4;                    // mtile16 base (q:0-31 k:32-63 v:64-95)
    const int ntb = b * 64 + n32 * 2;

    // this wave stages mtile mtb+w (hi+lo) each kt
    const unsigned short* Asrc_h = Ahi + (size_t)(mtb + w) * 8192 + lo8;
    const unsigned short* Asrc_l = Alo + (size_t)(mtb + w) * 8192 + lo8;

    f32x4 acc[4][2];
    #pragma unroll
    for (int i = 0; i < 4; ++i)
        #pragma unroll
        for (int j = 0; j < 2; ++j) acc[i][j] = (f32x4){0.f, 0.f, 0.f, 0.f};

    bf16x8 Bh[2][2], Bl[2][2];
    #pragma unroll
    for (int nt = 0; nt < 2; ++nt) {
        const size_t o = (size_t)(ntb + nt) * 8192 + lo8;
        Bh[0][nt] = *(const bf16x8*)(Bhi + o);
        Bl[0][nt] = *(const bf16x8*)(Blo + o);
    }
    // prologue: stage kt=0 A stripe
    *(bf16x8*)&As[0][w][0][lo8] = *(const bf16x8*)Asrc_h;
    *(bf16x8*)&As[0][w][1][lo8] = *(const bf16x8*)Asrc_l;
    __syncthreads();

    for (int kt = 0; kt < 16; ++kt) {
        const int cur = kt & 1, nxt = cur ^ 1;
        bf16x8 stgh, stgl;
        if (kt < 15) {
            const int kn = (kt + 1) * 512;
            // issue next-kt loads EARLY (latency hidden under MFMAs)
            stgh = *(const bf16x8*)(Asrc_h + kn);
            stgl = *(const bf16x8*)(Asrc_l + kn);
            #pragma unroll
            for (int nt = 0; nt < 2; ++nt) {
                const size_t o = (size_t)(ntb + nt) * 8192 + kn + lo8;
                Bh[nxt][nt] = *(const bf16x8*)(Bhi + o);
                Bl[nxt][nt] = *(const bf16x8*)(Blo + o);
            }
        }
        // A fragments from LDS (block-shared)
        bf16x8 Afh[4], Afl[4];
        #pragma unroll
        for (int mt = 0; mt < 4; ++mt) {
            Afh[mt] = *(const bf16x8*)&As[cur][mt][0][lo8];
            Afl[mt] = *(const bf16x8*)&As[cur][mt][1][lo8];
        }
        #pragma unroll
        for (int mt = 0; mt < 4; ++mt)
            #pragma unroll
            for (int nt = 0; nt < 2; ++nt) {
                f32x4 c = acc[mt][nt];
                c = __builtin_amdgcn_mfma_f32_16x16x32_bf16(Afh[mt], Bh[cur][nt], c, 0, 0, 0);
                c = __builtin_amdgcn_mfma_f32_16x16x32_bf16(Afh[mt], Bl[cur][nt], c, 0, 0, 0);
                c = __builtin_amdgcn_mfma_f32_16x16x32_bf16(Afl[mt], Bh[cur][nt], c, 0, 0, 0);
                acc[mt][nt] = c;
            }
        if (kt < 15) {
            // write staged A AFTER the MFMA cluster (vmcnt drains here)
            *(bf16x8*)&As[nxt][w][0][lo8] = stgh;
            *(bf16x8*)&As[nxt][w][1][lo8] = stgl;
        }
        __syncthreads();
    }

    // ---- epilogue: D[m=quad*4+r (channel)][n=l15 (time)] -> attn planes ----
    const int head = m64 & 7;
    const size_t hbase = ((size_t)(b * Hn + head) * 16) << 12;
    if (sel < 2) {
        const float* Bv = sel == 0 ? bq : bk;
        unsigned short* ph = sel == 0 ? qhi : khi;
        unsigned short* pl = sel == 0 ? qlo : klo;
        const float qscale = sel == 0 ? QK_SCALE : 1.0f;
        #pragma unroll
        for (int mt = 0; mt < 4; ++mt) {
            const int c0 = mt * 16 + quad * 4;          // channel-in-head base
            float bb[4];
            #pragma unroll
            for (int r = 0; r < 4; ++r) bb[r] = Bv[head * 64 + c0 + r];
            const int lane_out = (((c0 >> 3) & 3) << 4) + l15;
            const int e0 = c0 & 7;                      // 0 or 4
            const int cg = c0 >> 5;
            #pragma unroll
            for (int nt = 0; nt < 2; ++nt) {
                const int tile = n32 >> 1;
                const int rhi = (n32 & 1) * 2 + nt;     // (t&63)>>4
                const int g = rhi * 2 + cg;
                const size_t off = hbase + ((size_t)tile << 12) + g * 512
                                 + (size_t)lane_out * 8 + e0;
                ushort4 h4, l4;
                #pragma unroll
                for (int r = 0; r < 4; ++r) {
                    const float v = (acc[mt][nt][r] + bb[r]) * qscale;
                    const unsigned short hh = f2bf(v);
                    ((unsigned short*)&h4)[r] = hh;
                    ((unsigned short*)&l4)[r] = f2bf(v - bf16_f32(hh));
                }
                *(ushort4*)(ph + off) = h4;
                *(ushort4*)(pl + off) = l4;
            }
        }
    } else {
        #pragma unroll
        for (int mt = 0; mt < 4; ++mt) {
            const int c0 = mt * 16 + quad * 4;
            float bb[4];
            #pragma unroll
            for (int r = 0; r < 4; ++r) bb[r] = bv[head * 64 + c0 + r];
            #pragma unroll
            for (int nt = 0; nt < 2; ++nt) {
                const int t = n32 * 32 + nt * 16 + l15;
                const int tile = t >> 6, jl = t & 63;
                const int jg = jl >> 5, lanej = ((jl >> 3) & 3) << 4;
                const int e = jl & 7;
                const size_t tb = hbase + ((size_t)tile << 12);
                #pragma unroll
                for (int r = 0; r < 4; ++r) {
                    const int c = c0 + r;
                    const int g = mt * 2 + jg;          // c>>4 == mt here
                    const int lane_v = lanej + (c & 15);
                    const float v = acc[mt][nt][r] + bb[r];
                    const unsigned short hh = f2bf(v);
                    const size_t off = tb + g * 512 + (size_t)lane_v * 8 + e;
                    vhi[off] = hh;
                    vlo[off] = f2bf(v - bf16_f32(hh));
                }
            }
        }
    }
}

// ---------------------------------------------------------------------------
// Out-projection GEMM, R10 (unchanged): 64m x 64n block, 2x2 wave grid,
// BOTH operands staged + shared. 512 blocks (2/CU).
// ---------------------------------------------------------------------------
__global__ __launch_bounds__(256) void gemm_out(
    const unsigned short* __restrict__ Ahi, const unsigned short* __restrict__ Alo,
    const unsigned short* __restrict__ Bhi, const unsigned short* __restrict__ Blo,
    const float* __restrict__ bo, float* __restrict__ out)
{
    __shared__ alignas(16) unsigned short St[2][16][512];  // chunks: 0-7 A, 8-15 B

    const int tid = threadIdx.x;
    const int w = tid >> 6, lane = tid & 63;
    const int l15 = lane & 15, quad = lane >> 4;
    const int lo8 = lane << 3;

    const int id = blockIdx.x;
    const int xcd = id & 7, slot = id >> 3;       // 0..63
    const int ncol64 = xcd * 8 + (slot >> 3);     // 0..63 (8 n64-cols per XCD)
    const int mg8 = slot & 7;                     // 0..7 (64-row Wo group)
    const int wr = w >> 1, wc = w & 1;            // 2x2 wave grid
    const int m32 = mg8 * 2 + wr;                 // 0..15
    const int n32g = ncol64 * 2 + wc;             // 0..127
    const int b = n32g >> 5, n32 = n32g & 31;
    const int nb = (ncol64 & 15) * 4;             // block ntile base (in batch)
    const int bb64 = (ncol64 >> 4) * 64;          // batch ntile base

    // this wave's 4 staging chunks (chunk c = w*4+i)
    const unsigned short* csrc[4];
    #pragma unroll
    for (int i = 0; i < 4; ++i) {
        const int c = w * 4 + i;
        if (c < 8) {
            const int mt = c >> 1;
            csrc[i] = ((c & 1) ? Alo : Ahi) + (size_t)(96 + mg8 * 4 + mt) * 8192 + lo8;
        } else {
            const int nt = (c - 8) >> 1;
            csrc[i] = ((c & 1) ? Blo : Bhi) + (size_t)(bb64 + nb + nt) * 8192 + lo8;
        }
    }

    f32x4 acc[2][2];
    #pragma unroll
    for (int i = 0; i < 2; ++i)
        #pragma unroll
        for (int j = 0; j < 2; ++j) acc[i][j] = (f32x4){0.f, 0.f, 0.f, 0.f};

    // prologue: stage kt=0
    #pragma unroll
    for (int i = 0; i < 4; ++i)
        *(bf16x8*)&St[0][w * 4 + i][lo8] = *(const bf16x8*)csrc[i];
    __syncthreads();

    for (int kt = 0; kt < 16; ++kt) {
        const int cur = kt & 1, nxt = cur ^ 1;
        bf16x8 stg[4];
        if (kt < 15) {
            const int kn = (kt + 1) * 512;
            #pragma unroll
            for (int i = 0; i < 4; ++i)
                stg[i] = *(const bf16x8*)(csrc[i] + kn);
        }
        bf16x8 Afh[2], Afl[2], Bfh[2], Bfl[2];
        #pragma unroll
        for (int i = 0; i < 2; ++i) {
            const int lm = wr * 2 + i;
            Afh[i] = *(const bf16x8*)&St[cur][lm * 2 + 0][lo8];
            Afl[i] = *(const bf16x8*)&St[cur][lm * 2 + 1][lo8];
            const int ln = wc * 2 + i;
            Bfh[i] = *(const bf16x8*)&St[cur][8 + ln * 2 + 0][lo8];
            Bfl[i] = *(const bf16x8*)&St[cur][8 + ln * 2 + 1][lo8];
        }
        #pragma unroll
        for (int mt = 0; mt < 2; ++mt)
            #pragma unroll
            for (int nt = 0; nt < 2; ++nt) {
                f32x4 c = acc[mt][nt];
                c = __builtin_amdgcn_mfma_f32_16x16x32_bf16(Afh[mt], Bfh[nt], c, 0, 0, 0);
                c = __builtin_amdgcn_mfma_f32_16x16x32_bf16(Afh[mt], Bfl[nt], c, 0, 0, 0);
                c = __builtin_amdgcn_mfma_f32_16x16x32_bf16(Afl[mt], Bfh[nt], c, 0, 0, 0);
                acc[mt][nt] = c;
            }
        if (kt < 15) {
            #pragma unroll
            for (int i = 0; i < 4; ++i)
                *(bf16x8*)&St[nxt][w * 4 + i][lo8] = stg[i];
        }
        __syncthreads();
    }

    float* Ob = out + (size_t)b * Cdim * Tdim;
    #pragma unroll
    for (int mt = 0; mt < 2; ++mt) {
        const int m = m32 * 32 + mt * 16 + quad * 4;
        float bb[4];
        #pragma unroll
        for (int r = 0; r < 4; ++r) bb[r] = bo[m + r];
        #pragma unroll
        for (int nt = 0; nt < 2; ++nt) {
            const int t = n32 * 32 + nt * 16 + l15;
            #pragma unroll
            for (int r = 0; r < 4; ++r)
                Ob[(size_t)(m + r) * Tdim + t] = acc[mt][nt][r] + bb[r];
        }
    }
}

// ---------------------------------------------------------------------------
// R12 attention: R9 body (measured 54 us best) + ISOLATED T5 s_setprio
// around the QK^T and PV MFMA clusters. m191: +4-7% on attn with
// independent waves at different phases — exactly this kernel's regime
// (barrier-free after init, 8 free-running waves/CU). No other change.
// ---------------------------------------------------------------------------
__global__ __launch_bounds__(256) void attn_mfma(
    const unsigned short* __restrict__ qhi, const unsigned short* __restrict__ qlo,
    const unsigned short* __restrict__ khi, const unsigned short* __restrict__ klo,
    const unsigned short* __restrict__ vhi, const unsigned short* __restrict__ vlo,
    const float* __restrict__ ek,   // [9,64]
    const float* __restrict__ ev,   // [9,64]
    unsigned short* __restrict__ cxhi, unsigned short* __restrict__ cxlo)
{
    __shared__ alignas(16) unsigned short psh[4096], psl[4096];
    __shared__ float rk[576];       // rel-k logits (exp2 domain via q scale)
    __shared__ float evs[576];
    __shared__ float bandp[576];    // f32 post-exp P band values, wave-private rows

    const int tid = threadIdx.x;
    int it, h, b;
    {
        const int n = blockIdx.x;
        const int xcd = n & 7, slot = n >> 3;
        const int pair = (xcd << 2) | (slot >> 4);
        it = slot & 15;
        b = pair >> 3;
        h = pair & 7;
    }
    const int i0 = it * 64;
    const int lane = tid & 63, w = tid >> 6;
    const int l15 = lane & 15, quad = lane >> 4;
    const int m_blk = w * 16 + l15;
    const int lo8 = lane << 3;

    const size_t bh16 = (size_t)(b * Hn + h) * 16;

    bf16x8 qfh[2], qfl[2];
    {
        const unsigned short* qth = qhi + ((bh16 + it) << 12);
        const unsigned short* qtl = qlo + ((bh16 + it) << 12);
        #pragma unroll
        for (int ks = 0; ks < 2; ++ks) {
            qfh[ks] = *(const bf16x8*)(qth + (((w << 1) | ks) << 9) + lo8);
            qfl[ks] = *(const bf16x8*)(qtl + (((w << 1) | ks) << 9) + lo8);
        }
    }

    bf16x8 ekh[2], ekl[2];
    #pragma unroll
    for (int ks = 0; ks < 2; ++ks) {
        #pragma unroll
        for (int j = 0; j < 8; ++j) { ekh[ks][j] = 0; ekl[ks][j] = 0; }
        if (l15 < 9) {
            #pragma unroll
            for (int j = 0; j < 8; ++j) {
                const float v = ek[l15 * 64 + ks * 32 + quad * 8 + j];
                const unsigned short hh = f2bf(v);
                ekh[ks][j] = (short)hh;
                ekl[ks][j] = (short)f2bf(v - bf16_f32(hh));
            }
        }
    }

    {
        f32x4 rkD = (f32x4){0.f, 0.f, 0.f, 0.f};
        #pragma unroll
        for (int ks = 0; ks < 2; ++ks) {
            rkD = __builtin_amdgcn_mfma_f32_16x16x32_bf16(qfh[ks], ekh[ks], rkD, 0, 0, 0);
            rkD = __builtin_amdgcn_mfma_f32_16x16x32_bf16(qfh[ks], ekl[ks], rkD, 0, 0, 0);
            rkD = __builtin_amdgcn_mfma_f32_16x16x32_bf16(qfl[ks], ekh[ks], rkD, 0, 0, 0);
        }
        if (l15 < 9) {
            // q is pre-scaled -> rkD already carries QK_SCALE
            #pragma unroll
            for (int r = 0; r < 4; ++r)
                rk[(w * 16 + quad * 4 + r) * 9 + l15] = rkD[r];
        }
    }
    for (int idx = tid; idx < 576; idx += 256) evs[idx] = ev[idx];
    __syncthreads();   // the ONLY barrier

    // hoisted P-store swizzle addresses (constant per thread)
    int osw[4];
    #pragma unroll
    for (int jt = 0; jt < 4; ++jt) osw[jt] = sw(m_blk, jt * 16 + quad * 4);

    float m_run = -1e30f, l_run = 0.f;
    f32x4 Oc[4];
    #pragma unroll
    for (int ct = 0; ct < 4; ++ct) Oc[ct] = (f32x4){0.f, 0.f, 0.f, 0.f};

    const unsigned short* kh0 = khi + (bh16 << 12);
    const unsigned short* kl0 = klo + (bh16 << 12);
    const unsigned short* vh0 = vhi + (bh16 << 12);
    const unsigned short* vl0 = vlo + (bh16 << 12);

    for (int t = 0; t < 16; ++t) {
        const int j0 = t << 6;
        const size_t tb = (size_t)t << 12;
        const unsigned short* kht = kh0 + tb;
        const unsigned short* klt = kl0 + tb;
        const unsigned short* vht = vh0 + tb;
        const unsigned short* vlt = vl0 + tb;

        bf16x8 vbh[2][4], vbl[2][4];
        #pragma unroll
        for (int ks = 0; ks < 2; ++ks)
            #pragma unroll
            for (int ct = 0; ct < 4; ++ct) {
                vbh[ks][ct] = *(const bf16x8*)(vht + (((ct << 1) | ks) << 9) + lo8);
                vbl[ks][ct] = *(const bf16x8*)(vlt + (((ct << 1) | ks) << 9) + lo8);
            }

        f32x4 Sc[4];
        #pragma unroll
        for (int jt = 0; jt < 4; ++jt) Sc[jt] = (f32x4){0.f, 0.f, 0.f, 0.f};
        __builtin_amdgcn_s_setprio(1);
        #pragma unroll
        for (int ks = 0; ks < 2; ++ks) {
            bf16x8 ah[4], al[4];
            #pragma unroll
            for (int jt = 0; jt < 4; ++jt) {
                ah[jt] = *(const bf16x8*)(kht + (((jt << 1) | ks) << 9) + lo8);
                al[jt] = *(const bf16x8*)(klt + (((jt << 1) | ks) << 9) + lo8);
            }
            #pragma unroll
            for (int jt = 0; jt < 4; ++jt) {
                Sc[jt] = __builtin_amdgcn_mfma_f32_16x16x32_bf16(ah[jt], qfh[ks], Sc[jt], 0, 0, 0);
                Sc[jt] = __builtin_amdgcn_mfma_f32_16x16x32_bf16(ah[jt], qfl[ks], Sc[jt], 0, 0, 0);
                Sc[jt] = __builtin_amdgcn_mfma_f32_16x16x32_bf16(al[jt], qfh[ks], Sc[jt], 0, 0, 0);
            }
        }
        __builtin_amdgcn_s_setprio(0);

        const int dt = j0 - i0;
        const bool diag = (dt >= -67 && dt <= 67);
        if (diag) {
            #pragma unroll
            for (int jt = 0; jt < 4; ++jt) {
                const int db = dt + jt * 16 + quad * 4 - m_blk;
                #pragma unroll
                for (int r = 0; r < 4; ++r) {
                    const int d = db + r;
                    if ((unsigned)(d + 4) <= 8u) Sc[jt][r] += rk[m_blk * 9 + d + 4];
                }
            }
        }

        // row max: max3-shaped tree (v_max3_f32)
        const float t0m = max3f(Sc[0][0], Sc[0][1], Sc[0][2]);
        const float t1m = max3f(Sc[0][3], Sc[1][0], Sc[1][1]);
        const float t2m = max3f(Sc[1][2], Sc[1][3], Sc[2][0]);
        const float t3m = max3f(Sc[2][1], Sc[2][2], Sc[2][3]);
        const float t4m = max3f(Sc[3][0], Sc[3][1], Sc[3][2]);
        const float mt = fmaxf(max3f(t0m, t1m, t2m), max3f(t3m, t4m, Sc[3][3]));
        float mr = fmaxf(mt, __shfl_xor(mt, 16));
        mr = fmaxf(mr, __shfl_xor(mr, 32));

        // wave-uniform rescale skip: when no row's max grows, alpha==1 exactly
        if (__any(mr > m_run)) {
            const float mn = fmaxf(m_run, mr);
            const float alpha = __builtin_amdgcn_exp2f(m_run - mn);
            m_run = mn;
            l_run *= alpha;
            const float al0 = __shfl(alpha, quad * 4 + 0);
            const float al1 = __shfl(alpha, quad * 4 + 1);
            const float al2 = __shfl(alpha, quad * 4 + 2);
            const float al3 = __shfl(alpha, quad * 4 + 3);
            #pragma unroll
            for (int ct = 0; ct < 4; ++ct) {
                Oc[ct][0] *= al0; Oc[ct][1] *= al1; Oc[ct][2] *= al2; Oc[ct][3] *= al3;
            }
        }

        #pragma unroll
        for (int jt = 0; jt < 4; ++jt)
            #pragma unroll
            for (int r = 0; r < 4; ++r)
                Sc[jt][r] = __builtin_amdgcn_exp2f(Sc[jt][r] - m_run);

        float rs = ((Sc[0][0] + Sc[0][1]) + (Sc[0][2] + Sc[0][3]))
                 + ((Sc[1][0] + Sc[1][1]) + (Sc[1][2] + Sc[1][3]))
                 + ((Sc[2][0] + Sc[2][1]) + (Sc[2][2] + Sc[2][3]))
                 + ((Sc[3][0] + Sc[3][1]) + (Sc[3][2] + Sc[3][3]));
        rs += __shfl_xor(rs, 16);
        rs += __shfl_xor(rs, 32);
        l_run += rs;

        // f32 band scatter for rel-v (wave-private rows, read after PV)
        if (diag) {
            #pragma unroll
            for (int jt = 0; jt < 4; ++jt) {
                const int db = dt + jt * 16 + quad * 4 - m_blk;
                #pragma unroll
                for (int r = 0; r < 4; ++r) {
                    const int d = db + r;
                    if ((unsigned)(d + 4) <= 8u) bandp[m_blk * 9 + d + 4] = Sc[jt][r];
                }
            }
        }

        // P hi/lo split via native cvt (compiler pairs into v_cvt_pk_bf16_f32)
        #pragma unroll
        for (int jt = 0; jt < 4; ++jt) {
            ushort4 ph, pl;
            ph.x = f2bf(Sc[jt][0]); pl.x = f2bf(Sc[jt][0] - bf16_f32(ph.x));
            ph.y = f2bf(Sc[jt][1]); pl.y = f2bf(Sc[jt][1] - bf16_f32(ph.y));
            ph.z = f2bf(Sc[jt][2]); pl.z = f2bf(Sc[jt][2] - bf16_f32(ph.z));
            ph.w = f2bf(Sc[jt][3]); pl.w = f2bf(Sc[jt][3] - bf16_f32(ph.w));
            *(ushort4*)&psh[osw[jt]] = ph;
            *(ushort4*)&psl[osw[jt]] = pl;
        }
        // no barrier: wave reads only its own 16 P rows

        __builtin_amdgcn_s_setprio(1);
        #pragma unroll
        for (int ks = 0; ks < 2; ++ks) {
            bf16x8 pah = fragld(psh, m_blk, ks, quad);
            bf16x8 pal = fragld(psl, m_blk, ks, quad);
            #pragma unroll
            for (int ct = 0; ct < 4; ++ct) {
                Oc[ct] = __builtin_amdgcn_mfma_f32_16x16x32_bf16(pah, vbh[ks][ct], Oc[ct], 0, 0, 0);
                Oc[ct] = __builtin_amdgcn_mfma_f32_16x16x32_bf16(pah, vbl[ks][ct], Oc[ct], 0, 0, 0);
                Oc[ct] = __builtin_amdgcn_mfma_f32_16x16x32_bf16(pal, vbh[ks][ct], Oc[ct], 0, 0, 0);
            }
        }
        __builtin_amdgcn_s_setprio(0);

        if (diag) {
            #pragma unroll
            for (int r = 0; r < 4; ++r) {
                const int mrow = w * 16 + quad * 4 + r;
                const int ig = i0 + mrow;
                #pragma unroll
                for (int e = 0; e < 9; ++e) {
                    const int jl = ig + e - 4 - j0;
                    if ((unsigned)jl < 64u) {
                        const float p = bandp[mrow * 9 + e];   // f32 broadcast read
                        #pragma unroll
                        for (int ct = 0; ct < 4; ++ct)
                            Oc[ct][r] += p * evs[e * 64 + ct * 16 + l15];
                    }
                }
            }
        }
    }

    // ---- epilogue: normalize, write ctx B-operand frag-major hi/lo planes ----
    const float rlv = 1.f / l_run;
    float rl[4];
    rl[0] = __shfl(rlv, quad * 4 + 0);
    rl[1] = __shfl(rlv, quad * 4 + 1);
    rl[2] = __shfl(rlv, quad * 4 + 2);
    rl[3] = __shfl(rlv, quad * 4 + 3);
    const int ntile16 = it * 4 + w;
    const int e = l15 & 7;
    #pragma unroll
    for (int ct = 0; ct < 4; ++ct) {
        const int cl = ct * 16 + l15;                    // channel within head
        const int ktc = h * 2 + (cl >> 5);
        const int lane_c = (((ct * 2 + (l15 >> 3)) & 3) << 4) + quad * 4;   // + r
        const size_t base = (((size_t)(b * 64 + ntile16)) * 16 + ktc) * 512;
        #pragma unroll
        for (int r = 0; r < 4; ++r) {
            const float v = Oc[ct][r] * rl[r];
            const unsigned short hh = f2bf(v);
            const size_t off = base + (size_t)(lane_c + r) * 8 + e;
            cxhi[off] = hh;
            cxlo[off] = f2bf(v - bf16_f32(hh));
        }
    }
}

// ---------------------------------------------------------------------------
extern "C" void kernel_launch(void* const* d_in, const int* in_sizes, int n_in,
                              void* d_out, int out_size, void* d_ws, size_t ws_size,
                              hipStream_t stream) {
    const float* x  = (const float*)d_in[0];
    const float* wq = (const float*)d_in[1];
    const float* bq = (const float*)d_in[2];
    const float* wk = (const float*)d_in[3];
    const float* bk = (const float*)d_in[4];
    const float* wv = (const float*)d_in[5];
    const float* bv = (const float*)d_in[6];
    const float* wo = (const float*)d_in[7];
    const float* bo = (const float*)d_in[8];
    const float* ek = (const float*)d_in[9];
    const float* ev = (const float*)d_in[10];
    float* out = (float*)d_out;

    const size_t PW = 2048u * 512u;          // stacked-W plane elements
    const size_t PX = 4u * 1024u * 512u;     // X / ctx / attn plane elements
    unsigned short* WAhi = (unsigned short*)d_ws;
    unsigned short* WAlo = WAhi + PW;
    unsigned short* XBhi = WAlo + PW;
    unsigned short* XBlo = XBhi + PX;
    unsigned short* qhi  = XBlo + PX;
    unsigned short* qlo  = qhi + PX;
    unsigned short* khi  = qlo + PX;
    unsigned short* klo  = khi + PX;
    unsigned short* vhi  = klo + PX;
    unsigned short* vlo  = vhi + PX;
    unsigned short* cxhi = vlo + PX;
    unsigned short* cxlo = cxhi + PX;

    // one-time split/convert of W and X into frag-major planes
    prep_kernel<<<dim3(1024), 256, 0, stream>>>(
        wq, wk, wv, wo, x, WAhi, WAlo, XBhi, XBlo);

    // QKV projection: 768 blocks (3/CU), A-shared LDS dbuf -> attn planes
    gemm_qkv<<<dim3(768), 256, 0, stream>>>(
        WAhi, WAlo, XBhi, XBlo, bq, bk, bv,
        qhi, qlo, khi, klo, vhi, vlo);

    // barrier-free MFMA flash attention (diet + setprio) -> ctx planes
    attn_mfma<<<dim3(512), 256, 0, stream>>>(
        qhi, qlo, khi, klo, vhi, vlo, ek, ev, cxhi, cxlo);

    // output projection: 512 blocks (2/CU), A+B dual-shared LDS dbuf -> fp32
    gemm_out<<<dim3(512), 256, 0, stream>>>(
        WAhi, WAlo, cxhi, cxlo, bo, out);
}